// Round 15
// baseline (192.351 us; speedup 1.0000x reference)
//
#include <hip/hip_runtime.h>
#include <math.h>

// B=4, C=64, H=W=64, N=4096, NPIX=16384. All fp32 in/out.
// Pixel-major [pix][ch] pipeline. ws (floats), footprint 5M+256:
//  A ws+0..1M   : xT hi -> O0f|O1f (attn partials) -> c2T bf16
//  B ws+1M..2M  : c1T bf16 -> O2f|O3f
//  C ws+2M..3M  : thT f16 -> zT hi
//  D ws+3M..3.5M: phT f16
//  E ws+4M..4.5M: g16 (bf16 [B][C][N])
//  wp ws+4.5M   : FRAGMENT-PACKED weights (bf16 hi) ; part/lp ws+5M-65536 ;
//  stats ws+5M
//
// r37: r36/r33 (155.7-156.7 verified) with ONE attn change: K moves from
//  LDS to REGISTERS with one-step prefetch. K fragments are 16B/lane
//  contiguous in phT's global layout; same-(b,quarter) blocks share one
//  XCD (bx%8 fixed per xslot) so the 512KB K stream is XCD-L2-local.
//  QK(s) now issues at iteration top from regs (no barrier/lgkm wait);
//  kF loads for s+1 issue right after QK(s) (~400+ cyc of softmax+PV+
//  barrier cover L2 latency — fixes r27's zero-distance mistake).
//  K LDS writes/reads deleted; LDS 32KB -> 16KB (V only). Same
//  addresses + MFMA order -> bit-identical output.

typedef __attribute__((ext_vector_type(8))) short short8;
typedef __attribute__((ext_vector_type(8))) _Float16 half8;
typedef __attribute__((ext_vector_type(4))) float f32x4;

__device__ __forceinline__ ushort f2bf(float x) {
    unsigned u = __float_as_uint(x);
    unsigned r = (u + 0x7FFFu + ((u >> 16) & 1u)) >> 16;  // RNE
    return (ushort)r;
}
__device__ __forceinline__ float bf2f(ushort h) {
    return __uint_as_float(((unsigned)h) << 16);
}
__device__ __forceinline__ ushort f2h(float x) {  // fp32 -> fp16 bits (RNE)
    union { _Float16 h; ushort u; } c;
    c.h = (_Float16)x;
    return c.u;
}
__device__ __forceinline__ short8 ldfrag(const ushort* base, int row, int ch) {
    return *(const short8*)&base[(row << 6) + (((ch ^ (row & 7))) << 3)];
}

// ---------------------------------------------------------------------------
// prep_all: blocks <256: x -> xT [pix][ch] bf16 HI ONLY.
// blocks 256..975: 5x 3x3 weight sets -> fragment layout (bf16 hi only).
//   theta set (s==1) PRE-SCALED by log2e (softmax exp2 fold).
// blocks 976..991: 1x1 weights -> fragment layout (bf16 hi only).
// ---------------------------------------------------------------------------
__global__ __launch_bounds__(256) void prep_all_k(
    const float* __restrict__ x, ushort* __restrict__ xh,
    const float* __restrict__ w0, const float* __restrict__ w1,
    const float* __restrict__ w2, const float* __restrict__ w3,
    const float* __restrict__ w4, const float* __restrict__ w5,
    ushort* __restrict__ wbase)
{
    __shared__ __align__(16) float T[64 * 68];
    const int blk = blockIdx.x, t = threadIdx.x;
    if (blk < 256) {
        const int b = blk >> 6, n0 = (blk & 63) << 6;
        for (int p = t; p < 1024; p += 256) {
            int c = p >> 4, n4 = (p & 15) << 2;
            *(float4*)&T[c * 68 + n4] =
                *(const float4*)&x[(((size_t)(b * 64 + c)) << 12) + n0 + n4];
        }
        __syncthreads();
        for (int p = t; p < 1024; p += 256) {
            int n = p >> 4, c4 = (p & 15) << 2;
            size_t off = (((size_t)(b * 4096 + n0 + n)) << 6) + c4;
            ushort4 hi;
            hi.x = f2bf(T[(c4 + 0) * 68 + n]);
            hi.y = f2bf(T[(c4 + 1) * 68 + n]);
            hi.z = f2bf(T[(c4 + 2) * 68 + n]);
            hi.w = f2bf(T[(c4 + 3) * 68 + n]);
            *(ushort4*)&xh[off] = hi;
        }
    } else {
        const float* W[6] = {w0, w1, w2, w3, w4, w5};
        int q = blk - 256;
        if (q < 720) {
            int s = q / 144, bi = q - s * 144;
            int idx = bi * 256 + t;
            if (idx >= 36864) return;
            int co = idx / 576;
            int r = idx - co * 576;
            int ci = r / 9;
            int tap = r - ci * 9;
            float v = W[s][idx];
            if (s == 1) v *= 1.44269504f;   // theta *= log2e
            int cog = co >> 4, lc = co & 15;
            int kc = ci >> 5, qd = (ci >> 3) & 3, j = ci & 7;
            int lane = (qd << 4) + lc;
            ushort* dst = wbase + (size_t)s * 36864;
            dst[(((((tap << 1) + kc) << 2) + cog) << 9) + (lane << 3) + j] =
                f2bf(v);
        } else {
            int idx = (q - 720) * 256 + t;
            if (idx >= 4096) return;
            float v = W[5][idx];
            int co = idx >> 6, ci = idx & 63;
            int cog = co >> 4, lc = co & 15;
            int kc = ci >> 5, qd = (ci >> 3) & 3, j = ci & 7;
            int lane = (qd << 4) + lc;
            ushort* dst = wbase + 5 * 36864;
            dst[(((kc << 2) + cog) << 9) + (lane << 3) + j] = f2bf(v);
        }
    }
}

// ---------------------------------------------------------------------------
// MFMA 3x3 conv (bf16 compute). Block = 32 pix x 64 co, grid 512 (2 blk/CU).
// Wave tile 16pix x 32co. A-tile staged once per block in XOR-swizzled LDS.
// BNIN=1: read bf16 source, apply relu(v*sc+sh) inline while staging.
// MODE 0: bf16 out [pix][co] + BN partial stats -> part[bx*64+ch].
// MODE 1 (NOUT=3): theta -> f16 (bias *log2e); phi -> f16; g -> bf16.
// ---------------------------------------------------------------------------
template <int NOUT, int MODE, int BNIN, int ALO>
__global__ __launch_bounds__(256) void conv_mfma_k(
    const ushort* __restrict__ Ah, const ushort* __restrict__ Al,
    const ushort* __restrict__ Afb,
    const float* __restrict__ bnsc, const float* __restrict__ bnsh,
    const ushort* __restrict__ w0f, const ushort* __restrict__ w1f,
    const ushort* __restrict__ w2f,
    const float* __restrict__ b0, const float* __restrict__ b1,
    const float* __restrict__ b2,
    ushort* __restrict__ outB, float* __restrict__ part,
    ushort* __restrict__ o0h, ushort* __restrict__ o1h,
    ushort* __restrict__ o2t)
{
    __shared__ __align__(16) ushort AhS[102 * 64];
    __shared__ __align__(16) ushort AlS[ALO ? 102 * 64 : 64];
    __shared__ float redS[4][32], redSS[4][32];
    const int t = threadIdx.x, lane = t & 63, wv = t >> 6;
    const int quad = lane >> 4, l15 = lane & 15;
    const int bx = blockIdx.x;
    const int row = bx >> 1;                            // b*64 + h
    const int h = row & 63;
    const int half = bx & 1;
    const int wb0 = (half << 5) + ((wv >> 1) << 4);     // wave pixel base (w)
    const int chalf = (wv & 1) << 5;

    const ushort* wf[3] = {w0f, w1f, w2f};

    // ---- stage rows h-1..h+1 x 34 halo pixels (w = half*32-1 .. +32)
    for (int u = t; u < 816; u += 256) {
        int R = u >> 3, ch = u & 7;
        int dhIdx = (R >= 68) ? 2 : ((R >= 34) ? 1 : 0);
        int po = R - dhIdx * 34;
        int hh = h + dhIdx - 1;
        int gw = (half << 5) - 1 + po;
        short8 vh = {0, 0, 0, 0, 0, 0, 0, 0};
        short8 vl = {0, 0, 0, 0, 0, 0, 0, 0};
        if (((unsigned)hh < 64u) & ((unsigned)gw < 64u)) {
            size_t base =
                (((size_t)(((row + dhIdx - 1) << 6) + gw)) << 6) + (ch << 3);
            if (BNIN) {
                short8 raw = *(const short8*)&Afb[base];
                float4 sa = *(const float4*)&bnsc[ch << 3];
                float4 sb = *(const float4*)&bnsc[(ch << 3) + 4];
                float4 ha4 = *(const float4*)&bnsh[ch << 3];
                float4 hb4 = *(const float4*)&bnsh[(ch << 3) + 4];
                float rr[8];
                rr[0] = fmaxf(bf2f((ushort)raw[0]) * sa.x + ha4.x, 0.f);
                rr[1] = fmaxf(bf2f((ushort)raw[1]) * sa.y + ha4.y, 0.f);
                rr[2] = fmaxf(bf2f((ushort)raw[2]) * sa.z + ha4.z, 0.f);
                rr[3] = fmaxf(bf2f((ushort)raw[3]) * sa.w + ha4.w, 0.f);
                rr[4] = fmaxf(bf2f((ushort)raw[4]) * sb.x + hb4.x, 0.f);
                rr[5] = fmaxf(bf2f((ushort)raw[5]) * sb.y + hb4.y, 0.f);
                rr[6] = fmaxf(bf2f((ushort)raw[6]) * sb.z + hb4.z, 0.f);
                rr[7] = fmaxf(bf2f((ushort)raw[7]) * sb.w + hb4.w, 0.f);
#pragma unroll
                for (int j = 0; j < 8; ++j) {
                    ushort hx = f2bf(rr[j]);
                    vh[j] = (short)hx;
                    if (ALO) vl[j] = (short)f2bf(rr[j] - bf2f(hx));
                }
            } else {
                vh = *(const short8*)&Ah[base];
                if (ALO) vl = *(const short8*)&Al[base];
            }
        }
        int so = (R << 6) + ((ch ^ (R & 7)) << 3);
        *(short8*)&AhS[so] = vh;
        if (ALO) *(short8*)&AlS[so] = vl;
    }
    __syncthreads();

    f32x4 acc[NOUT][2];
#pragma unroll
    for (int o = 0; o < NOUT; ++o)
#pragma unroll
        for (int cb = 0; cb < 2; ++cb)
#pragma unroll
            for (int j = 0; j < 4; ++j) acc[o][cb][j] = 0.f;

#pragma unroll
    for (int dhIdx = 0; dhIdx < 3; ++dhIdx)
#pragma unroll
        for (int dw = -1; dw <= 1; ++dw) {
            const int tap = dhIdx * 3 + (dw + 1);
#pragma unroll
            for (int kc = 0; kc < 2; ++kc) {
                int R = dhIdx * 34 + 1 + ((wv >> 1) << 4) + l15 + dw;
                short8 aH = ldfrag(AhS, R, (kc << 2) + quad);
                short8 aL = {0, 0, 0, 0, 0, 0, 0, 0};
                if (ALO) aL = ldfrag(AlS, R, (kc << 2) + quad);
#pragma unroll
                for (int o = 0; o < NOUT; ++o)
#pragma unroll
                    for (int cb = 0; cb < 2; ++cb) {
                        int cog = ((wv & 1) << 1) + cb;
                        short8 bH = *(const short8*)
                            &wf[o][(((((tap << 1) + kc) << 2) + cog) << 9) +
                                   (lane << 3)];
                        acc[o][cb] = __builtin_amdgcn_mfma_f32_16x16x32_bf16(
                            aH, bH, acc[o][cb], 0, 0, 0);
                        if (o == 0 && ALO)
                            acc[o][cb] = __builtin_amdgcn_mfma_f32_16x16x32_bf16(
                                aL, bH, acc[o][cb], 0, 0, 0);
                    }
            }
        }

    if constexpr (MODE == 0) {
        float s_[2], ss_[2];
#pragma unroll
        for (int cb = 0; cb < 2; ++cb) {
            int co = chalf + (cb << 4) + l15;
            float s = 0.f, ss = 0.f;
#pragma unroll
            for (int r = 0; r < 4; ++r) {
                int pix = (row << 6) + wb0 + (quad << 2) + r;
                float v = acc[0][cb][r];
                outB[(((size_t)pix) << 6) + co] = f2bf(v);
                s += v;
                ss += v * v;
            }
            s_[cb] = s;
            ss_[cb] = ss;
        }
#pragma unroll
        for (int off = 16; off < 64; off <<= 1) {
#pragma unroll
            for (int cb = 0; cb < 2; ++cb) {
                s_[cb] += __shfl_xor(s_[cb], off);
                ss_[cb] += __shfl_xor(ss_[cb], off);
            }
        }
        if (quad == 0) {
#pragma unroll
            for (int cb = 0; cb < 2; ++cb) {
                redS[wv][(cb << 4) + l15] = s_[cb];
                redSS[wv][(cb << 4) + l15] = ss_[cb];
            }
        }
        __syncthreads();
        if (t < 64) {
            int w01 = (t >> 5) & 1;  // chalf bit
            float S = redS[w01][t & 31] + redS[w01 + 2][t & 31];
            float SS = redSS[w01][t & 31] + redSS[w01 + 2][t & 31];
            part[bx * 64 + t] = S;
            part[32768 + bx * 64 + t] = SS;
        }
    } else {
        const int b = row >> 6;
#pragma unroll
        for (int cb = 0; cb < 2; ++cb) {
            int co = chalf + (cb << 4) + l15;
            float bth = b0[co] * 1.44269504f;   // theta bias *log2e
            float bph = b1[co], bg = b2[co];
            int pixb = (row << 6) + wb0 + (quad << 2);
#pragma unroll
            for (int r = 0; r < 4; ++r) {
                size_t off = (((size_t)(pixb + r)) << 6) + co;
                o0h[off] = f2h(acc[0][cb][r] + bth);                 // theta f16
                o1h[off] = f2h(acc[NOUT > 1 ? 1 : 0][cb][r] + bph);  // phi f16
            }
            int n0 = pixb & 4095;
            ushort4 gv;
            gv.x = f2bf(acc[NOUT - 1][cb][0] + bg);
            gv.y = f2bf(acc[NOUT - 1][cb][1] + bg);
            gv.z = f2bf(acc[NOUT - 1][cb][2] + bg);
            gv.w = f2bf(acc[NOUT - 1][cb][3] + bg);
            *(ushort4*)&o2t[(((size_t)b) << 18) + (((size_t)co) << 12) + n0] = gv;
        }
    }
}

// ---------------------------------------------------------------------------
// statsB: 64 blocks (one wave per channel): reduce 512 block-partials ->
// BN scale/shift.
// ---------------------------------------------------------------------------
__global__ __launch_bounds__(64) void statsB_k(
    const float* __restrict__ part, const float* __restrict__ gamma,
    const float* __restrict__ beta, float* __restrict__ scale,
    float* __restrict__ shift)
{
    const int c = blockIdx.x, t = threadIdx.x;
    float S = 0.f, SS = 0.f;
#pragma unroll
    for (int i = 0; i < 8; ++i) {
        int k = t + (i << 6);
        S += part[k * 64 + c];
        SS += part[32768 + k * 64 + c];
    }
#pragma unroll
    for (int off = 32; off > 0; off >>= 1) {
        S += __shfl_down(S, off);
        SS += __shfl_down(SS, off);
    }
    if (t == 0) {
        float mean = S * (1.f / 16384.f);
        float var = SS * (1.f / 16384.f) - mean * mean;
        float sc = gamma[c] * rsqrtf(var + 1e-5f);
        scale[c] = sc;
        shift[c] = beta[c] - mean * sc;
    }
}

// ---------------------------------------------------------------------------
// Flash attention, register-resident P, register-resident K (r37).
// Q-tile 64, 4-way KV split, grid 1024 (4 blk/CU). XCD swizzle: bx&15 ->
// (b, quarter) — same-(b,quarter) blocks share an XCD, so the 512KB K
// stream is XCD-L2-local. 16 steps. Per wave: 16-q-row strip x 64 k.
// K fragments (16B/lane contiguous in phT) live in kF[8] REGISTERS with
// one-step prefetch: QK(s) issues at iteration top with zero waits;
// kF loads for s+1 issue right after QK(s) and their L2 latency hides
// under softmax+PV+barrier. V stays LDS double-buffered (16KB).
// S^T = mfma_f32_16x16x32_f16 single pass; softmax = single
// exp2(S - 30*log2e) (theta pre-scaled by log2e upstream).
// P truncating-bf16; PV/l bf16. s_setprio(1) around MFMA clusters.
// Partial O bf16-hi (ushort4); partial l fp32.
// ---------------------------------------------------------------------------
__global__ __launch_bounds__(256) void attn_k(
    const ushort* __restrict__ thT, const ushort* __restrict__ phT,
    const ushort* __restrict__ g16,
    ushort* __restrict__ O0f, ushort* __restrict__ O1f,
    ushort* __restrict__ O2f, ushort* __restrict__ O3f,
    float* __restrict__ lp)
{
    __shared__ __align__(16) ushort Vt[2][4096];

    const int t = threadIdx.x;
    const int bx = blockIdx.x;
    const int xslot = bx & 15;
    const int b = xslot & 3;
    const int quarter = xslot >> 2;
    const int q0 = (bx >> 4) << 6;      // 64-row q tile
    const int mbase = quarter << 10;
    const int lane = t & 63;
    const int wv = t >> 6;
    const int quad = lane >> 4;
    const int l15 = lane & 15;
    const int qrow = (wv << 4) + l15;   // wave's q row (0..63)

    const size_t cb64 = ((size_t)b) << 18;
    const ushort* Qg = thT + cb64 + (((size_t)q0) << 6);
    const ushort* Kh_g = phT + cb64;
    const ushort* Vg = g16 + cb64;
    ushort* Ops[4] = {O0f, O1f, O2f, O3f};
    ushort* Op = Ops[quarter];
    float* lpd = lp + (quarter << 14);

    // Q fragments (f16) as B-operand: col = qrow, k = ks*32+quad*8+j
    half8 qF[2];
#pragma unroll
    for (int ks = 0; ks < 2; ++ks) {
        size_t off = (((size_t)qrow) << 6) + ks * 32 + quad * 8;
        qF[ks] = *(const half8*)&Qg[off];
    }

    // K fragments in registers: kF[kt*2+ks] for the CURRENT step.
    // Preload step 0 (each wave reads the full 8KB K tile; L2/XCD-local).
    half8 kF[8];
#pragma unroll
    for (int kt = 0; kt < 4; ++kt)
#pragma unroll
        for (int ks = 0; ks < 2; ++ks)
            kF[(kt << 1) + ks] = *(const half8*)
                &Kh_g[((mbase + (kt << 4) + l15) << 6) + ks * 32 + quad * 8];

    // stage step-0 V tile (bf16)
#pragma unroll
    for (int rd = 0; rd < 2; ++rd) {
        int ii = rd * 256 + t;
        int row = ii >> 3, ch = ii & 7;
        int off = (row << 6) + ((ch ^ (row & 7)) << 3);
        *(short8*)&Vt[0][off] =
            *(const short8*)&Vg[(row << 12) + mbase + (ch << 3)];
    }

    f32x4 oaccT[4];
    f32x4 lacc;
#pragma unroll
    for (int j = 0; j < 4; ++j) lacc[j] = 0.f;
#pragma unroll
    for (int ct = 0; ct < 4; ++ct)
#pragma unroll
        for (int j = 0; j < 4; ++j) oaccT[ct][j] = 0.f;

    short8 onesB;  // bf16 A-operand row 0 = ones (lanes l15==0)
    {
        short ov = (l15 == 0) ? (short)0x3F80 : (short)0;
#pragma unroll
        for (int j = 0; j < 8; ++j) onesB[j] = ov;
    }

    const float M2 = 43.2808512f;   // 30 * log2e

    for (int step = 0; step < 16; ++step) {
        const int buf = step & 1;
        __syncthreads();

        short8 rV[2];
        if (step < 15) {
            const int m1 = mbase + ((step + 1) << 6);
#pragma unroll
            for (int rd = 0; rd < 2; ++rd) {
                int ii = rd * 256 + t;
                int row = ii >> 3, ch = ii & 7;
                rV[rd] = *(const short8*)&Vg[(row << 12) + m1 + (ch << 3)];
            }
        }

        // S^T tiles from REGISTER K: sacc2[kt] holds k = kt*16+quad*4+r,
        // q-col = l15. No LDS read, no barrier dependency.
        f32x4 sacc2[4];
        __builtin_amdgcn_s_setprio(1);
#pragma unroll
        for (int kt = 0; kt < 4; ++kt) {
#pragma unroll
            for (int j = 0; j < 4; ++j) sacc2[kt][j] = 0.f;
#pragma unroll
            for (int ks = 0; ks < 2; ++ks)
                sacc2[kt] = __builtin_amdgcn_mfma_f32_16x16x32_f16(
                    kF[(kt << 1) + ks], qF[ks], sacc2[kt], 0, 0, 0);
        }
        __builtin_amdgcn_s_setprio(0);

        // prefetch K fragments for step+1 (QK consumed current values;
        // L2 latency hides under softmax + PV + barrier)
        if (step < 15) {
            const int m1 = mbase + ((step + 1) << 6);
#pragma unroll
            for (int kt = 0; kt < 4; ++kt)
#pragma unroll
                for (int ks = 0; ks < 2; ++ks)
                    kF[(kt << 1) + ks] = *(const half8*)
                        &Kh_g[((m1 + (kt << 4) + l15) << 6) +
                              ks * 32 + quad * 8];
        }

        // softmax numerator: single exp2 + truncating-bf16 pack
        unsigned pk0[4], pk1[4];
#pragma unroll
        for (int kt = 0; kt < 4; ++kt) {
            float e0 = __builtin_amdgcn_exp2f(sacc2[kt][0] - M2);
            float e1 = __builtin_amdgcn_exp2f(sacc2[kt][1] - M2);
            float e2 = __builtin_amdgcn_exp2f(sacc2[kt][2] - M2);
            float e3 = __builtin_amdgcn_exp2f(sacc2[kt][3] - M2);
            pk0[kt] = __builtin_amdgcn_perm(__float_as_uint(e1),
                                            __float_as_uint(e0), 0x07060302u);
            pk1[kt] = __builtin_amdgcn_perm(__float_as_uint(e3),
                                            __float_as_uint(e2), 0x07060302u);
        }

        // route: dst quad d gets src quads {2d,2d+1 mod 4} of kt pair ->
        // pb[ks] = P^T B-fragment, k = ks*32 + quad*8 + j.
        short8 pb[2];
#pragma unroll
        for (int ks = 0; ks < 2; ++ks) {
            unsigned a0 = pk0[2 * ks], b0v = pk0[2 * ks + 1];
            asm("s_nop 1\n\t"
                "v_permlane32_swap_b32 %0, %1\n\t"
                "s_nop 1\n\t"
                "v_permlane16_swap_b32 %0, %1\n\t"
                "s_nop 1"
                : "+v"(a0), "+v"(b0v));
            unsigned a1 = pk1[2 * ks], b1v = pk1[2 * ks + 1];
            asm("s_nop 1\n\t"
                "v_permlane32_swap_b32 %0, %1\n\t"
                "s_nop 1\n\t"
                "v_permlane16_swap_b32 %0, %1\n\t"
                "s_nop 1"
                : "+v"(a1), "+v"(b1v));
            union { unsigned u[4]; short8 s; } cv;
            cv.u[0] = a0;   // j0,j1
            cv.u[1] = a1;   // j2,j3
            cv.u[2] = b0v;  // j4,j5
            cv.u[3] = b1v;  // j6,j7
            pb[ks] = cv.s;
        }

        // l += ones . P^T ; O^T += V^T . P^T (bf16 path)
        __builtin_amdgcn_s_setprio(1);
#pragma unroll
        for (int ks = 0; ks < 2; ++ks)
            lacc = __builtin_amdgcn_mfma_f32_16x16x32_bf16(
                onesB, pb[ks], lacc, 0, 0, 0);
#pragma unroll
        for (int ct = 0; ct < 4; ++ct)
#pragma unroll
            for (int ks = 0; ks < 2; ++ks) {
                short8 vb = ldfrag(&Vt[buf][0], (ct << 4) + l15,
                                   (ks << 2) + quad);
                oaccT[ct] = __builtin_amdgcn_mfma_f32_16x16x32_bf16(
                    vb, pb[ks], oaccT[ct], 0, 0, 0);
            }
        __builtin_amdgcn_s_setprio(0);

        if (step < 15) {
#pragma unroll
            for (int rd = 0; rd < 2; ++rd) {
                int ii = rd * 256 + t;
                int row = ii >> 3, ch = ii & 7;
                int off = (row << 6) + ((ch ^ (row & 7)) << 3);
                *(short8*)&Vt[buf ^ 1][off] = rV[rd];
            }
        }
    }

    // epilogue: partial l (tile row 0 = quad 0, reg 0) + partial O^T
    const int nq = q0 + qrow;
    if (quad == 0) lpd[(b << 12) + nq] = lacc[0];
#pragma unroll
    for (int ct = 0; ct < 4; ++ct) {
        ushort4 ov;
        ov.x = f2bf(oaccT[ct][0]);
        ov.y = f2bf(oaccT[ct][1]);
        ov.z = f2bf(oaccT[ct][2]);
        ov.w = f2bf(oaccT[ct][3]);
        *(ushort4*)&Op[cb64 + (((size_t)nq) << 6) + (ct << 4) + (quad << 2)] =
            ov;
    }
}

// ---------------------------------------------------------------------------
// 1x1 conv + bias + residual, MFMA (fragment-packed W, bf16), with
// FUSED 4-way attention reduce: y = (ΣOq)/(Σlq), in-register bf16 hi/lo.
// zT written HI ONLY.
// ---------------------------------------------------------------------------
__global__ __launch_bounds__(256) void conv1x1_k(
    const ushort* __restrict__ O0f, const ushort* __restrict__ O1f,
    const ushort* __restrict__ O2f, const ushort* __restrict__ O3f,
    const float* __restrict__ lp,
    const ushort* __restrict__ wf,
    const float* __restrict__ Wb, const float* __restrict__ x,
    ushort* __restrict__ zh)
{
    const int t = threadIdx.x, lane = t & 63, wv = t >> 6;
    const int quad = lane >> 4, l15 = lane & 15;
    const int chalf = (wv & 1) << 5;
    const int P0 = blockIdx.x << 5;
    const int pbase = P0 + ((wv >> 1) << 4);
    const int b = P0 >> 12;
    const int pix = pbase + l15;   // A row (global pixel)
    const float linv = 1.f / (lp[pix] + lp[16384 + pix] +
                              lp[32768 + pix] + lp[49152 + pix]);

    f32x4 acc[2];
#pragma unroll
    for (int j = 0; j < 4; ++j) { acc[0][j] = 0.f; acc[1][j] = 0.f; }

#pragma unroll
    for (int kc = 0; kc < 2; ++kc) {
        const int k0 = kc * 32 + quad * 8;
        size_t ao = (((size_t)pix) << 6) + k0;
        short8 p0 = *(const short8*)&O0f[ao];
        short8 p1 = *(const short8*)&O1f[ao];
        short8 p2 = *(const short8*)&O2f[ao];
        short8 p3 = *(const short8*)&O3f[ao];
        short8 aH, aL;
#pragma unroll
        for (int j = 0; j < 8; ++j) {
            float v = (bf2f((ushort)p0[j]) + bf2f((ushort)p1[j]) +
                       bf2f((ushort)p2[j]) + bf2f((ushort)p3[j])) * linv;
            ushort hh = f2bf(v);
            aH[j] = (short)hh;
            aL[j] = (short)f2bf(v - bf2f(hh));
        }
#pragma unroll
        for (int cb = 0; cb < 2; ++cb) {
            int cog = ((wv & 1) << 1) + cb;
            short8 bH = *(const short8*)
                &wf[(((kc << 2) + cog) << 9) + (lane << 3)];
            acc[cb] = __builtin_amdgcn_mfma_f32_16x16x32_bf16(aH, bH, acc[cb], 0, 0, 0);
            acc[cb] = __builtin_amdgcn_mfma_f32_16x16x32_bf16(aL, bH, acc[cb], 0, 0, 0);
        }
    }

    const int pixb = pbase + (quad << 2);
    const int n0 = pixb & 4095;
#pragma unroll
    for (int cb = 0; cb < 2; ++cb) {
        int co = chalf + (cb << 4) + l15;
        float bias = Wb[co];
        float4 xr = *(const float4*)&x[(((size_t)(b * 64 + co)) << 12) + n0];
        float xa[4] = {xr.x, xr.y, xr.z, xr.w};
#pragma unroll
        for (int r = 0; r < 4; ++r) {
            float v = acc[cb][r] + bias + xa[r];
            size_t off = (((size_t)(pixb + r)) << 6) + co;
            zh[off] = f2bf(v);
        }
    }
}

// ---------------------------------------------------------------------------
// Final: BN2 apply + relu + transpose back to [B][C][H][W]. c2T is bf16.
// ---------------------------------------------------------------------------
__global__ __launch_bounds__(256) void bnreluT_k(
    const ushort* __restrict__ c2T, const float* __restrict__ sc,
    const float* __restrict__ sh, float* __restrict__ out)
{
    __shared__ __align__(16) float T[64 * 68];
    const int b = blockIdx.x >> 6, n0 = (blockIdx.x & 63) << 6, t = threadIdx.x;
    for (int p = t; p < 1024; p += 256) {
        int n = p >> 4, c4 = (p & 15) << 2;
        ushort4 v = *(const ushort4*)&c2T[(((size_t)(b * 4096 + n0 + n)) << 6) + c4];
        float4 s4 = *(const float4*)&sc[c4];
        float4 h4 = *(const float4*)&sh[c4];
        T[(c4 + 0) * 68 + n] = fmaxf(bf2f(v.x) * s4.x + h4.x, 0.f);
        T[(c4 + 1) * 68 + n] = fmaxf(bf2f(v.y) * s4.y + h4.y, 0.f);
        T[(c4 + 2) * 68 + n] = fmaxf(bf2f(v.z) * s4.z + h4.z, 0.f);
        T[(c4 + 3) * 68 + n] = fmaxf(bf2f(v.w) * s4.w + h4.w, 0.f);
    }
    __syncthreads();
    for (int p = t; p < 1024; p += 256) {
        int c = p >> 4, n4 = (p & 15) << 2;
        float4 r;
        r.x = T[c * 68 + n4 + 0];
        r.y = T[c * 68 + n4 + 1];
        r.z = T[c * 68 + n4 + 2];
        r.w = T[c * 68 + n4 + 3];
        *(float4*)&out[(((size_t)(b * 64 + c)) << 12) + n0 + n4] = r;
    }
}

// ---------------------------------------------------------------------------
extern "C" void kernel_launch(void* const* d_in, const int* in_sizes, int n_in,
                              void* d_out, int out_size, void* d_ws,
                              size_t ws_size, hipStream_t stream)
{
    const float* x    = (const float*)d_in[0];
    const float* c1w  = (const float*)d_in[1];
    const float* bn1g = (const float*)d_in[2];
    const float* bn1b = (const float*)d_in[3];
    const float* thw  = (const float*)d_in[4];
    const float* thb  = (const float*)d_in[5];
    const float* phw  = (const float*)d_in[6];
    const float* phb  = (const float*)d_in[7];
    const float* gw   = (const float*)d_in[8];
    const float* gb   = (const float*)d_in[9];
    const float* Wwt  = (const float*)d_in[10];
    const float* Wbs  = (const float*)d_in[11];
    const float* c2w  = (const float*)d_in[12];
    const float* bn2g = (const float*)d_in[13];
    const float* bn2b = (const float*)d_in[14];
    float* out = (float*)d_out;

    float* ws = (float*)d_ws;
    // region A: xT hi -> O0f|O1f (bf16-hi partials) -> c2T bf16
    ushort* xT_hi = (ushort*)ws;
    ushort* O0f = (ushort*)ws;                       // 1M ushorts
    ushort* O1f = (ushort*)(ws + (1 << 19));         // 1M ushorts
    ushort* c2Tb = (ushort*)ws;                      // 1M ushorts
    // region B: c1T bf16 -> O2f|O3f
    ushort* c1Tb = (ushort*)(ws + (1 << 20));        // 1M ushorts
    ushort* O2f = (ushort*)(ws + (1 << 20));
    ushort* O3f = (ushort*)(ws + (1 << 20) + (1 << 19));
    // region C: thT f16 -> zT hi
    ushort* thT = (ushort*)(ws + (2 << 20));
    ushort* zT_hi = thT;
    // regions D/E
    ushort* phT = (ushort*)(ws + (3 << 20));
    ushort* g16 = (ushort*)(ws + (4 << 20));
    // weights (fragment-packed, bf16 hi) / partials+lp / stats
    ushort* wp = (ushort*)(ws + (9 << 19));
    float* part = ws + (5 << 20) - 65536;  // also lp (4x16384) for attention
    float* stats = ws + (5 << 20);
    float* sc1 = stats, *sh1 = stats + 64, *sc2 = stats + 128, *sh2 = stats + 192;

    ushort* wc1f = wp;
    ushort* wthf = wp + 1 * 36864;
    ushort* wphf = wp + 2 * 36864;
    ushort* wgf  = wp + 3 * 36864;
    ushort* wc2f = wp + 4 * 36864;
    ushort* w11f = wp + 5 * 36864;

    prep_all_k<<<992, 256, 0, stream>>>(x, xT_hi, c1w, thw, phw, gw,
                                        c2w, Wwt, wp);
    conv_mfma_k<1, 0, 0, 0><<<512, 256, 0, stream>>>(
        xT_hi, nullptr, nullptr, nullptr, nullptr,
        wc1f, nullptr, nullptr, nullptr, nullptr, nullptr,
        c1Tb, part, nullptr, nullptr, nullptr);
    statsB_k<<<64, 64, 0, stream>>>(part, bn1g, bn1b, sc1, sh1);
    conv_mfma_k<3, 1, 1, 0><<<512, 256, 0, stream>>>(
        nullptr, nullptr, c1Tb, sc1, sh1,
        wthf, wphf, wgf, thb, phb, gb,
        nullptr, nullptr, thT, phT, g16);
    attn_k<<<1024, 256, 0, stream>>>(thT, phT, g16,
                                     O0f, O1f, O2f, O3f, part);
    conv1x1_k<<<512, 256, 0, stream>>>(O0f, O1f, O2f, O3f, part, w11f, Wbs, x,
                                       zT_hi);
    conv_mfma_k<1, 0, 0, 0><<<512, 256, 0, stream>>>(
        zT_hi, nullptr, nullptr, nullptr, nullptr,
        wc2f, nullptr, nullptr, nullptr, nullptr, nullptr,
        c2Tb, part, nullptr, nullptr, nullptr);
    statsB_k<<<64, 64, 0, stream>>>(part, bn2g, bn2b, sc2, sh2);
    bnreluT_k<<<256, 256, 0, stream>>>(c2Tb, sc2, sh2, out);
}

// Round 16
// 155.698 us; speedup vs baseline: 1.2354x; 1.2354x over previous
//
#include <hip/hip_runtime.h>
#include <math.h>

// B=4, C=64, H=W=64, N=4096, NPIX=16384. All fp32 in/out.
// Pixel-major [pix][ch] pipeline. ws (floats), footprint 5M+256:
//  A ws+0..1M   : xT hi -> O0f|O1f (attn partials) -> c2T bf16
//  B ws+1M..2M  : c1T bf16 -> O2f|O3f
//  C ws+2M..3M  : thT f16 -> zT hi
//  D ws+3M..3.5M: phT f16
//  E ws+4M..4.5M: g16 (bf16 [B][C][N])
//  wp ws+4.5M   : FRAGMENT-PACKED weights (bf16 hi) ; part/lp ws+5M-65536 ;
//  stats ws+5M
//
// r38 = FINAL: exact r33/r36 champion (155.7-156.7 verified).
//  r37's register-K (69.8us attn, Mfma 10.5%) confirmed for the 2nd time
//  that cooperative LDS K-staging (one copy per block, shared by 4 waves)
//  is structurally essential; per-wave global K is L2-latency-bound.
//  Champion = register-P attn (permlane routing), fp16 single-pass QK,
//  exp2-folded softmax (theta pre-scaled by log2e), setprio on MFMA
//  clusters, 64-q tiles grid 1024, K/V double-buffered LDS.

typedef __attribute__((ext_vector_type(8))) short short8;
typedef __attribute__((ext_vector_type(8))) _Float16 half8;
typedef __attribute__((ext_vector_type(4))) float f32x4;

__device__ __forceinline__ ushort f2bf(float x) {
    unsigned u = __float_as_uint(x);
    unsigned r = (u + 0x7FFFu + ((u >> 16) & 1u)) >> 16;  // RNE
    return (ushort)r;
}
__device__ __forceinline__ float bf2f(ushort h) {
    return __uint_as_float(((unsigned)h) << 16);
}
__device__ __forceinline__ ushort f2h(float x) {  // fp32 -> fp16 bits (RNE)
    union { _Float16 h; ushort u; } c;
    c.h = (_Float16)x;
    return c.u;
}
__device__ __forceinline__ short8 ldfrag(const ushort* base, int row, int ch) {
    return *(const short8*)&base[(row << 6) + (((ch ^ (row & 7))) << 3)];
}
__device__ __forceinline__ half8 ldfragh(const ushort* base, int row, int ch) {
    return *(const half8*)&base[(row << 6) + (((ch ^ (row & 7))) << 3)];
}

// ---------------------------------------------------------------------------
// prep_all: blocks <256: x -> xT [pix][ch] bf16 HI ONLY.
// blocks 256..975: 5x 3x3 weight sets -> fragment layout (bf16 hi only).
//   theta set (s==1) PRE-SCALED by log2e (softmax exp2 fold).
// blocks 976..991: 1x1 weights -> fragment layout (bf16 hi only).
// ---------------------------------------------------------------------------
__global__ __launch_bounds__(256) void prep_all_k(
    const float* __restrict__ x, ushort* __restrict__ xh,
    const float* __restrict__ w0, const float* __restrict__ w1,
    const float* __restrict__ w2, const float* __restrict__ w3,
    const float* __restrict__ w4, const float* __restrict__ w5,
    ushort* __restrict__ wbase)
{
    __shared__ __align__(16) float T[64 * 68];
    const int blk = blockIdx.x, t = threadIdx.x;
    if (blk < 256) {
        const int b = blk >> 6, n0 = (blk & 63) << 6;
        for (int p = t; p < 1024; p += 256) {
            int c = p >> 4, n4 = (p & 15) << 2;
            *(float4*)&T[c * 68 + n4] =
                *(const float4*)&x[(((size_t)(b * 64 + c)) << 12) + n0 + n4];
        }
        __syncthreads();
        for (int p = t; p < 1024; p += 256) {
            int n = p >> 4, c4 = (p & 15) << 2;
            size_t off = (((size_t)(b * 4096 + n0 + n)) << 6) + c4;
            ushort4 hi;
            hi.x = f2bf(T[(c4 + 0) * 68 + n]);
            hi.y = f2bf(T[(c4 + 1) * 68 + n]);
            hi.z = f2bf(T[(c4 + 2) * 68 + n]);
            hi.w = f2bf(T[(c4 + 3) * 68 + n]);
            *(ushort4*)&xh[off] = hi;
        }
    } else {
        const float* W[6] = {w0, w1, w2, w3, w4, w5};
        int q = blk - 256;
        if (q < 720) {
            int s = q / 144, bi = q - s * 144;
            int idx = bi * 256 + t;
            if (idx >= 36864) return;
            int co = idx / 576;
            int r = idx - co * 576;
            int ci = r / 9;
            int tap = r - ci * 9;
            float v = W[s][idx];
            if (s == 1) v *= 1.44269504f;   // theta *= log2e
            int cog = co >> 4, lc = co & 15;
            int kc = ci >> 5, qd = (ci >> 3) & 3, j = ci & 7;
            int lane = (qd << 4) + lc;
            ushort* dst = wbase + (size_t)s * 36864;
            dst[(((((tap << 1) + kc) << 2) + cog) << 9) + (lane << 3) + j] =
                f2bf(v);
        } else {
            int idx = (q - 720) * 256 + t;
            if (idx >= 4096) return;
            float v = W[5][idx];
            int co = idx >> 6, ci = idx & 63;
            int cog = co >> 4, lc = co & 15;
            int kc = ci >> 5, qd = (ci >> 3) & 3, j = ci & 7;
            int lane = (qd << 4) + lc;
            ushort* dst = wbase + 5 * 36864;
            dst[(((kc << 2) + cog) << 9) + (lane << 3) + j] = f2bf(v);
        }
    }
}

// ---------------------------------------------------------------------------
// MFMA 3x3 conv (bf16 compute). Block = 32 pix x 64 co, grid 512 (2 blk/CU).
// Wave tile 16pix x 32co. A-tile staged once per block in XOR-swizzled LDS.
// BNIN=1: read bf16 source, apply relu(v*sc+sh) inline while staging.
// MODE 0: bf16 out [pix][co] + BN partial stats -> part[bx*64+ch].
// MODE 1 (NOUT=3): theta -> f16 (bias *log2e); phi -> f16; g -> bf16.
// ---------------------------------------------------------------------------
template <int NOUT, int MODE, int BNIN, int ALO>
__global__ __launch_bounds__(256) void conv_mfma_k(
    const ushort* __restrict__ Ah, const ushort* __restrict__ Al,
    const ushort* __restrict__ Afb,
    const float* __restrict__ bnsc, const float* __restrict__ bnsh,
    const ushort* __restrict__ w0f, const ushort* __restrict__ w1f,
    const ushort* __restrict__ w2f,
    const float* __restrict__ b0, const float* __restrict__ b1,
    const float* __restrict__ b2,
    ushort* __restrict__ outB, float* __restrict__ part,
    ushort* __restrict__ o0h, ushort* __restrict__ o1h,
    ushort* __restrict__ o2t)
{
    __shared__ __align__(16) ushort AhS[102 * 64];
    __shared__ __align__(16) ushort AlS[ALO ? 102 * 64 : 64];
    __shared__ float redS[4][32], redSS[4][32];
    const int t = threadIdx.x, lane = t & 63, wv = t >> 6;
    const int quad = lane >> 4, l15 = lane & 15;
    const int bx = blockIdx.x;
    const int row = bx >> 1;                            // b*64 + h
    const int h = row & 63;
    const int half = bx & 1;
    const int wb0 = (half << 5) + ((wv >> 1) << 4);     // wave pixel base (w)
    const int chalf = (wv & 1) << 5;

    const ushort* wf[3] = {w0f, w1f, w2f};

    // ---- stage rows h-1..h+1 x 34 halo pixels (w = half*32-1 .. +32)
    for (int u = t; u < 816; u += 256) {
        int R = u >> 3, ch = u & 7;
        int dhIdx = (R >= 68) ? 2 : ((R >= 34) ? 1 : 0);
        int po = R - dhIdx * 34;
        int hh = h + dhIdx - 1;
        int gw = (half << 5) - 1 + po;
        short8 vh = {0, 0, 0, 0, 0, 0, 0, 0};
        short8 vl = {0, 0, 0, 0, 0, 0, 0, 0};
        if (((unsigned)hh < 64u) & ((unsigned)gw < 64u)) {
            size_t base =
                (((size_t)(((row + dhIdx - 1) << 6) + gw)) << 6) + (ch << 3);
            if (BNIN) {
                short8 raw = *(const short8*)&Afb[base];
                float4 sa = *(const float4*)&bnsc[ch << 3];
                float4 sb = *(const float4*)&bnsc[(ch << 3) + 4];
                float4 ha4 = *(const float4*)&bnsh[ch << 3];
                float4 hb4 = *(const float4*)&bnsh[(ch << 3) + 4];
                float rr[8];
                rr[0] = fmaxf(bf2f((ushort)raw[0]) * sa.x + ha4.x, 0.f);
                rr[1] = fmaxf(bf2f((ushort)raw[1]) * sa.y + ha4.y, 0.f);
                rr[2] = fmaxf(bf2f((ushort)raw[2]) * sa.z + ha4.z, 0.f);
                rr[3] = fmaxf(bf2f((ushort)raw[3]) * sa.w + ha4.w, 0.f);
                rr[4] = fmaxf(bf2f((ushort)raw[4]) * sb.x + hb4.x, 0.f);
                rr[5] = fmaxf(bf2f((ushort)raw[5]) * sb.y + hb4.y, 0.f);
                rr[6] = fmaxf(bf2f((ushort)raw[6]) * sb.z + hb4.z, 0.f);
                rr[7] = fmaxf(bf2f((ushort)raw[7]) * sb.w + hb4.w, 0.f);
#pragma unroll
                for (int j = 0; j < 8; ++j) {
                    ushort hx = f2bf(rr[j]);
                    vh[j] = (short)hx;
                    if (ALO) vl[j] = (short)f2bf(rr[j] - bf2f(hx));
                }
            } else {
                vh = *(const short8*)&Ah[base];
                if (ALO) vl = *(const short8*)&Al[base];
            }
        }
        int so = (R << 6) + ((ch ^ (R & 7)) << 3);
        *(short8*)&AhS[so] = vh;
        if (ALO) *(short8*)&AlS[so] = vl;
    }
    __syncthreads();

    f32x4 acc[NOUT][2];
#pragma unroll
    for (int o = 0; o < NOUT; ++o)
#pragma unroll
        for (int cb = 0; cb < 2; ++cb)
#pragma unroll
            for (int j = 0; j < 4; ++j) acc[o][cb][j] = 0.f;

#pragma unroll
    for (int dhIdx = 0; dhIdx < 3; ++dhIdx)
#pragma unroll
        for (int dw = -1; dw <= 1; ++dw) {
            const int tap = dhIdx * 3 + (dw + 1);
#pragma unroll
            for (int kc = 0; kc < 2; ++kc) {
                int R = dhIdx * 34 + 1 + ((wv >> 1) << 4) + l15 + dw;
                short8 aH = ldfrag(AhS, R, (kc << 2) + quad);
                short8 aL = {0, 0, 0, 0, 0, 0, 0, 0};
                if (ALO) aL = ldfrag(AlS, R, (kc << 2) + quad);
#pragma unroll
                for (int o = 0; o < NOUT; ++o)
#pragma unroll
                    for (int cb = 0; cb < 2; ++cb) {
                        int cog = ((wv & 1) << 1) + cb;
                        short8 bH = *(const short8*)
                            &wf[o][(((((tap << 1) + kc) << 2) + cog) << 9) +
                                   (lane << 3)];
                        acc[o][cb] = __builtin_amdgcn_mfma_f32_16x16x32_bf16(
                            aH, bH, acc[o][cb], 0, 0, 0);
                        if (o == 0 && ALO)
                            acc[o][cb] = __builtin_amdgcn_mfma_f32_16x16x32_bf16(
                                aL, bH, acc[o][cb], 0, 0, 0);
                    }
            }
        }

    if constexpr (MODE == 0) {
        float s_[2], ss_[2];
#pragma unroll
        for (int cb = 0; cb < 2; ++cb) {
            int co = chalf + (cb << 4) + l15;
            float s = 0.f, ss = 0.f;
#pragma unroll
            for (int r = 0; r < 4; ++r) {
                int pix = (row << 6) + wb0 + (quad << 2) + r;
                float v = acc[0][cb][r];
                outB[(((size_t)pix) << 6) + co] = f2bf(v);
                s += v;
                ss += v * v;
            }
            s_[cb] = s;
            ss_[cb] = ss;
        }
#pragma unroll
        for (int off = 16; off < 64; off <<= 1) {
#pragma unroll
            for (int cb = 0; cb < 2; ++cb) {
                s_[cb] += __shfl_xor(s_[cb], off);
                ss_[cb] += __shfl_xor(ss_[cb], off);
            }
        }
        if (quad == 0) {
#pragma unroll
            for (int cb = 0; cb < 2; ++cb) {
                redS[wv][(cb << 4) + l15] = s_[cb];
                redSS[wv][(cb << 4) + l15] = ss_[cb];
            }
        }
        __syncthreads();
        if (t < 64) {
            int w01 = (t >> 5) & 1;  // chalf bit
            float S = redS[w01][t & 31] + redS[w01 + 2][t & 31];
            float SS = redSS[w01][t & 31] + redSS[w01 + 2][t & 31];
            part[bx * 64 + t] = S;
            part[32768 + bx * 64 + t] = SS;
        }
    } else {
        const int b = row >> 6;
#pragma unroll
        for (int cb = 0; cb < 2; ++cb) {
            int co = chalf + (cb << 4) + l15;
            float bth = b0[co] * 1.44269504f;   // theta bias *log2e
            float bph = b1[co], bg = b2[co];
            int pixb = (row << 6) + wb0 + (quad << 2);
#pragma unroll
            for (int r = 0; r < 4; ++r) {
                size_t off = (((size_t)(pixb + r)) << 6) + co;
                o0h[off] = f2h(acc[0][cb][r] + bth);                 // theta f16
                o1h[off] = f2h(acc[NOUT > 1 ? 1 : 0][cb][r] + bph);  // phi f16
            }
            int n0 = pixb & 4095;
            ushort4 gv;
            gv.x = f2bf(acc[NOUT - 1][cb][0] + bg);
            gv.y = f2bf(acc[NOUT - 1][cb][1] + bg);
            gv.z = f2bf(acc[NOUT - 1][cb][2] + bg);
            gv.w = f2bf(acc[NOUT - 1][cb][3] + bg);
            *(ushort4*)&o2t[(((size_t)b) << 18) + (((size_t)co) << 12) + n0] = gv;
        }
    }
}

// ---------------------------------------------------------------------------
// statsB: 64 blocks (one wave per channel): reduce 512 block-partials ->
// BN scale/shift.
// ---------------------------------------------------------------------------
__global__ __launch_bounds__(64) void statsB_k(
    const float* __restrict__ part, const float* __restrict__ gamma,
    const float* __restrict__ beta, float* __restrict__ scale,
    float* __restrict__ shift)
{
    const int c = blockIdx.x, t = threadIdx.x;
    float S = 0.f, SS = 0.f;
#pragma unroll
    for (int i = 0; i < 8; ++i) {
        int k = t + (i << 6);
        S += part[k * 64 + c];
        SS += part[32768 + k * 64 + c];
    }
#pragma unroll
    for (int off = 32; off > 0; off >>= 1) {
        S += __shfl_down(S, off);
        SS += __shfl_down(SS, off);
    }
    if (t == 0) {
        float mean = S * (1.f / 16384.f);
        float var = SS * (1.f / 16384.f) - mean * mean;
        float sc = gamma[c] * rsqrtf(var + 1e-5f);
        scale[c] = sc;
        shift[c] = beta[c] - mean * sc;
    }
}

// ---------------------------------------------------------------------------
// Flash attention, register-resident P. Q-tile 64, 4-way KV split,
// grid 1024 (4 blk/CU). XCD swizzle: bx&15 -> (b, quarter). 16 steps.
// Per wave: 16-q-row strip x 64 k.
// S^T = mfma_f32_16x16x32_f16(K_f16, Q_f16) single pass; theta (and its
// bias) pre-scaled by log2e upstream, so softmax is a single v_exp_f32:
// P = exp2(S - 30*log2e) == e^(s-30). P truncating-bf16; V bf16;
// PV/l bf16. s_setprio(1) around QK and PV MFMA clusters (T5).
// exp2 + v_perm pack; permlane32/16_swap (s_nop-padded) routes P.
// K/V double-buffered LDS (32KB). Partial O bf16-hi; partial l fp32.
// ---------------------------------------------------------------------------
__global__ __launch_bounds__(256) void attn_k(
    const ushort* __restrict__ thT, const ushort* __restrict__ phT,
    const ushort* __restrict__ g16,
    ushort* __restrict__ O0f, ushort* __restrict__ O1f,
    ushort* __restrict__ O2f, ushort* __restrict__ O3f,
    float* __restrict__ lp)
{
    __shared__ __align__(16) ushort Khi[2][4096];
    __shared__ __align__(16) ushort Vt[2][4096];

    const int t = threadIdx.x;
    const int bx = blockIdx.x;
    const int xslot = bx & 15;
    const int b = xslot & 3;
    const int quarter = xslot >> 2;
    const int q0 = (bx >> 4) << 6;      // 64-row q tile
    const int mbase = quarter << 10;
    const int lane = t & 63;
    const int wv = t >> 6;
    const int quad = lane >> 4;
    const int l15 = lane & 15;
    const int qrow = (wv << 4) + l15;   // wave's q row (0..63)

    const size_t cb64 = ((size_t)b) << 18;
    const ushort* Qg = thT + cb64 + (((size_t)q0) << 6);
    const ushort* Kh_g = phT + cb64;
    const ushort* Vg = g16 + cb64;
    ushort* Ops[4] = {O0f, O1f, O2f, O3f};
    ushort* Op = Ops[quarter];
    float* lpd = lp + (quarter << 14);

    // Q fragments (f16) as B-operand: col = qrow, k = ks*32+quad*8+j
    half8 qF[2];
#pragma unroll
    for (int ks = 0; ks < 2; ++ks) {
        size_t off = (((size_t)qrow) << 6) + ks * 32 + quad * 8;
        qF[ks] = *(const half8*)&Qg[off];
    }

    // stage step-0 K (f16) and V (bf16) tiles
#pragma unroll
    for (int rd = 0; rd < 2; ++rd) {
        int ii = rd * 256 + t;
        int row = ii >> 3, ch = ii & 7;
        int off = (row << 6) + ((ch ^ (row & 7)) << 3);
        *(short8*)&Khi[0][off] =
            *(const short8*)&Kh_g[((mbase + row) << 6) + (ch << 3)];
        *(short8*)&Vt[0][off] =
            *(const short8*)&Vg[(row << 12) + mbase + (ch << 3)];
    }

    f32x4 oaccT[4];
    f32x4 lacc;
#pragma unroll
    for (int j = 0; j < 4; ++j) lacc[j] = 0.f;
#pragma unroll
    for (int ct = 0; ct < 4; ++ct)
#pragma unroll
        for (int j = 0; j < 4; ++j) oaccT[ct][j] = 0.f;

    short8 onesB;  // bf16 A-operand row 0 = ones (lanes l15==0)
    {
        short ov = (l15 == 0) ? (short)0x3F80 : (short)0;
#pragma unroll
        for (int j = 0; j < 8; ++j) onesB[j] = ov;
    }

    const float M2 = 43.2808512f;   // 30 * log2e

    for (int step = 0; step < 16; ++step) {
        const int buf = step & 1;
        __syncthreads();

        short8 rKh[2], rV[2];
        if (step < 15) {
            const int m1 = mbase + ((step + 1) << 6);
#pragma unroll
            for (int rd = 0; rd < 2; ++rd) {
                int ii = rd * 256 + t;
                int row = ii >> 3, ch = ii & 7;
                rKh[rd] = *(const short8*)&Kh_g[((m1 + row) << 6) + (ch << 3)];
                rV[rd] = *(const short8*)&Vg[(row << 12) + m1 + (ch << 3)];
            }
        }

        // S^T tiles: sacc2[kt] holds k = kt*16+quad*4+r, q-col = l15.
        f32x4 sacc2[4];
        __builtin_amdgcn_s_setprio(1);
#pragma unroll
        for (int kt = 0; kt < 4; ++kt) {
#pragma unroll
            for (int j = 0; j < 4; ++j) sacc2[kt][j] = 0.f;
#pragma unroll
            for (int ks = 0; ks < 2; ++ks) {
                half8 bK = ldfragh(&Khi[buf][0], (kt << 4) + l15,
                                   (ks << 2) + quad);
                sacc2[kt] = __builtin_amdgcn_mfma_f32_16x16x32_f16(
                    bK, qF[ks], sacc2[kt], 0, 0, 0);
            }
        }
        __builtin_amdgcn_s_setprio(0);

        // softmax numerator: single exp2 + truncating-bf16 pack
        unsigned pk0[4], pk1[4];
#pragma unroll
        for (int kt = 0; kt < 4; ++kt) {
            float e0 = __builtin_amdgcn_exp2f(sacc2[kt][0] - M2);
            float e1 = __builtin_amdgcn_exp2f(sacc2[kt][1] - M2);
            float e2 = __builtin_amdgcn_exp2f(sacc2[kt][2] - M2);
            float e3 = __builtin_amdgcn_exp2f(sacc2[kt][3] - M2);
            pk0[kt] = __builtin_amdgcn_perm(__float_as_uint(e1),
                                            __float_as_uint(e0), 0x07060302u);
            pk1[kt] = __builtin_amdgcn_perm(__float_as_uint(e3),
                                            __float_as_uint(e2), 0x07060302u);
        }

        // route: dst quad d gets src quads {2d,2d+1 mod 4} of kt pair ->
        // pb[ks] = P^T B-fragment, k = ks*32 + quad*8 + j.
        short8 pb[2];
#pragma unroll
        for (int ks = 0; ks < 2; ++ks) {
            unsigned a0 = pk0[2 * ks], b0v = pk0[2 * ks + 1];
            asm("s_nop 1\n\t"
                "v_permlane32_swap_b32 %0, %1\n\t"
                "s_nop 1\n\t"
                "v_permlane16_swap_b32 %0, %1\n\t"
                "s_nop 1"
                : "+v"(a0), "+v"(b0v));
            unsigned a1 = pk1[2 * ks], b1v = pk1[2 * ks + 1];
            asm("s_nop 1\n\t"
                "v_permlane32_swap_b32 %0, %1\n\t"
                "s_nop 1\n\t"
                "v_permlane16_swap_b32 %0, %1\n\t"
                "s_nop 1"
                : "+v"(a1), "+v"(b1v));
            union { unsigned u[4]; short8 s; } cv;
            cv.u[0] = a0;   // j0,j1
            cv.u[1] = a1;   // j2,j3
            cv.u[2] = b0v;  // j4,j5
            cv.u[3] = b1v;  // j6,j7
            pb[ks] = cv.s;
        }

        // l += ones . P^T ; O^T += V^T . P^T (bf16 path)
        __builtin_amdgcn_s_setprio(1);
#pragma unroll
        for (int ks = 0; ks < 2; ++ks)
            lacc = __builtin_amdgcn_mfma_f32_16x16x32_bf16(
                onesB, pb[ks], lacc, 0, 0, 0);
#pragma unroll
        for (int ct = 0; ct < 4; ++ct)
#pragma unroll
            for (int ks = 0; ks < 2; ++ks) {
                short8 vb = ldfrag(&Vt[buf][0], (ct << 4) + l15,
                                   (ks << 2) + quad);
                oaccT[ct] = __builtin_amdgcn_mfma_f32_16x16x32_bf16(
                    vb, pb[ks], oaccT[ct], 0, 0, 0);
            }
        __builtin_amdgcn_s_setprio(0);

        if (step < 15) {
#pragma unroll
            for (int rd = 0; rd < 2; ++rd) {
                int ii = rd * 256 + t;
                int row = ii >> 3, ch = ii & 7;
                int off = (row << 6) + ((ch ^ (row & 7)) << 3);
                *(short8*)&Khi[buf ^ 1][off] = rKh[rd];
                *(short8*)&Vt[buf ^ 1][off] = rV[rd];
            }
        }
    }

    // epilogue: partial l (tile row 0 = quad 0, reg 0) + partial O^T
    const int nq = q0 + qrow;
    if (quad == 0) lpd[(b << 12) + nq] = lacc[0];
#pragma unroll
    for (int ct = 0; ct < 4; ++ct) {
        ushort4 ov;
        ov.x = f2bf(oaccT[ct][0]);
        ov.y = f2bf(oaccT[ct][1]);
        ov.z = f2bf(oaccT[ct][2]);
        ov.w = f2bf(oaccT[ct][3]);
        *(ushort4*)&Op[cb64 + (((size_t)nq) << 6) + (ct << 4) + (quad << 2)] =
            ov;
    }
}

// ---------------------------------------------------------------------------
// 1x1 conv + bias + residual, MFMA (fragment-packed W, bf16), with
// FUSED 4-way attention reduce: y = (ΣOq)/(Σlq), in-register bf16 hi/lo.
// zT written HI ONLY.
// ---------------------------------------------------------------------------
__global__ __launch_bounds__(256) void conv1x1_k(
    const ushort* __restrict__ O0f, const ushort* __restrict__ O1f,
    const ushort* __restrict__ O2f, const ushort* __restrict__ O3f,
    const float* __restrict__ lp,
    const ushort* __restrict__ wf,
    const float* __restrict__ Wb, const float* __restrict__ x,
    ushort* __restrict__ zh)
{
    const int t = threadIdx.x, lane = t & 63, wv = t >> 6;
    const int quad = lane >> 4, l15 = lane & 15;
    const int chalf = (wv & 1) << 5;
    const int P0 = blockIdx.x << 5;
    const int pbase = P0 + ((wv >> 1) << 4);
    const int b = P0 >> 12;
    const int pix = pbase + l15;   // A row (global pixel)
    const float linv = 1.f / (lp[pix] + lp[16384 + pix] +
                              lp[32768 + pix] + lp[49152 + pix]);

    f32x4 acc[2];
#pragma unroll
    for (int j = 0; j < 4; ++j) { acc[0][j] = 0.f; acc[1][j] = 0.f; }

#pragma unroll
    for (int kc = 0; kc < 2; ++kc) {
        const int k0 = kc * 32 + quad * 8;
        size_t ao = (((size_t)pix) << 6) + k0;
        short8 p0 = *(const short8*)&O0f[ao];
        short8 p1 = *(const short8*)&O1f[ao];
        short8 p2 = *(const short8*)&O2f[ao];
        short8 p3 = *(const short8*)&O3f[ao];
        short8 aH, aL;
#pragma unroll
        for (int j = 0; j < 8; ++j) {
            float v = (bf2f((ushort)p0[j]) + bf2f((ushort)p1[j]) +
                       bf2f((ushort)p2[j]) + bf2f((ushort)p3[j])) * linv;
            ushort hh = f2bf(v);
            aH[j] = (short)hh;
            aL[j] = (short)f2bf(v - bf2f(hh));
        }
#pragma unroll
        for (int cb = 0; cb < 2; ++cb) {
            int cog = ((wv & 1) << 1) + cb;
            short8 bH = *(const short8*)
                &wf[(((kc << 2) + cog) << 9) + (lane << 3)];
            acc[cb] = __builtin_amdgcn_mfma_f32_16x16x32_bf16(aH, bH, acc[cb], 0, 0, 0);
            acc[cb] = __builtin_amdgcn_mfma_f32_16x16x32_bf16(aL, bH, acc[cb], 0, 0, 0);
        }
    }

    const int pixb = pbase + (quad << 2);
    const int n0 = pixb & 4095;
#pragma unroll
    for (int cb = 0; cb < 2; ++cb) {
        int co = chalf + (cb << 4) + l15;
        float bias = Wb[co];
        float4 xr = *(const float4*)&x[(((size_t)(b * 64 + co)) << 12) + n0];
        float xa[4] = {xr.x, xr.y, xr.z, xr.w};
#pragma unroll
        for (int r = 0; r < 4; ++r) {
            float v = acc[cb][r] + bias + xa[r];
            size_t off = (((size_t)(pixb + r)) << 6) + co;
            zh[off] = f2bf(v);
        }
    }
}

// ---------------------------------------------------------------------------
// Final: BN2 apply + relu + transpose back to [B][C][H][W]. c2T is bf16.
// ---------------------------------------------------------------------------
__global__ __launch_bounds__(256) void bnreluT_k(
    const ushort* __restrict__ c2T, const float* __restrict__ sc,
    const float* __restrict__ sh, float* __restrict__ out)
{
    __shared__ __align__(16) float T[64 * 68];
    const int b = blockIdx.x >> 6, n0 = (blockIdx.x & 63) << 6, t = threadIdx.x;
    for (int p = t; p < 1024; p += 256) {
        int n = p >> 4, c4 = (p & 15) << 2;
        ushort4 v = *(const ushort4*)&c2T[(((size_t)(b * 4096 + n0 + n)) << 6) + c4];
        float4 s4 = *(const float4*)&sc[c4];
        float4 h4 = *(const float4*)&sh[c4];
        T[(c4 + 0) * 68 + n] = fmaxf(bf2f(v.x) * s4.x + h4.x, 0.f);
        T[(c4 + 1) * 68 + n] = fmaxf(bf2f(v.y) * s4.y + h4.y, 0.f);
        T[(c4 + 2) * 68 + n] = fmaxf(bf2f(v.z) * s4.z + h4.z, 0.f);
        T[(c4 + 3) * 68 + n] = fmaxf(bf2f(v.w) * s4.w + h4.w, 0.f);
    }
    __syncthreads();
    for (int p = t; p < 1024; p += 256) {
        int c = p >> 4, n4 = (p & 15) << 2;
        float4 r;
        r.x = T[c * 68 + n4 + 0];
        r.y = T[c * 68 + n4 + 1];
        r.z = T[c * 68 + n4 + 2];
        r.w = T[c * 68 + n4 + 3];
        *(float4*)&out[(((size_t)(b * 64 + c)) << 12) + n0 + n4] = r;
    }
}

// ---------------------------------------------------------------------------
extern "C" void kernel_launch(void* const* d_in, const int* in_sizes, int n_in,
                              void* d_out, int out_size, void* d_ws,
                              size_t ws_size, hipStream_t stream)
{
    const float* x    = (const float*)d_in[0];
    const float* c1w  = (const float*)d_in[1];
    const float* bn1g = (const float*)d_in[2];
    const float* bn1b = (const float*)d_in[3];
    const float* thw  = (const float*)d_in[4];
    const float* thb  = (const float*)d_in[5];
    const float* phw  = (const float*)d_in[6];
    const float* phb  = (const float*)d_in[7];
    const float* gw   = (const float*)d_in[8];
    const float* gb   = (const float*)d_in[9];
    const float* Wwt  = (const float*)d_in[10];
    const float* Wbs  = (const float*)d_in[11];
    const float* c2w  = (const float*)d_in[12];
    const float* bn2g = (const float*)d_in[13];
    const float* bn2b = (const float*)d_in[14];
    float* out = (float*)d_out;

    float* ws = (float*)d_ws;
    // region A: xT hi -> O0f|O1f (bf16-hi partials) -> c2T bf16
    ushort* xT_hi = (ushort*)ws;
    ushort* O0f = (ushort*)ws;                       // 1M ushorts
    ushort* O1f = (ushort*)(ws + (1 << 19));         // 1M ushorts
    ushort* c2Tb = (ushort*)ws;                      // 1M ushorts
    // region B: c1T bf16 -> O2f|O3f
    ushort* c1Tb = (ushort*)(ws + (1 << 20));        // 1M ushorts
    ushort* O2f = (ushort*)(ws + (1 << 20));
    ushort* O3f = (ushort*)(ws + (1 << 20) + (1 << 19));
    // region C: thT f16 -> zT hi
    ushort* thT = (ushort*)(ws + (2 << 20));
    ushort* zT_hi = thT;
    // regions D/E
    ushort* phT = (ushort*)(ws + (3 << 20));
    ushort* g16 = (ushort*)(ws + (4 << 20));
    // weights (fragment-packed, bf16 hi) / partials+lp / stats
    ushort* wp = (ushort*)(ws + (9 << 19));
    float* part = ws + (5 << 20) - 65536;  // also lp (4x16384) for attention
    float* stats = ws + (5 << 20);
    float* sc1 = stats, *sh1 = stats + 64, *sc2 = stats + 128, *sh2 = stats + 192;

    ushort* wc1f = wp;
    ushort* wthf = wp + 1 * 36864;
    ushort* wphf = wp + 2 * 36864;
    ushort* wgf  = wp + 3 * 36864;
    ushort* wc2f = wp + 4 * 36864;
    ushort* w11f = wp + 5 * 36864;

    prep_all_k<<<992, 256, 0, stream>>>(x, xT_hi, c1w, thw, phw, gw,
                                        c2w, Wwt, wp);
    conv_mfma_k<1, 0, 0, 0><<<512, 256, 0, stream>>>(
        xT_hi, nullptr, nullptr, nullptr, nullptr,
        wc1f, nullptr, nullptr, nullptr, nullptr, nullptr,
        c1Tb, part, nullptr, nullptr, nullptr);
    statsB_k<<<64, 64, 0, stream>>>(part, bn1g, bn1b, sc1, sh1);
    conv_mfma_k<3, 1, 1, 0><<<512, 256, 0, stream>>>(
        nullptr, nullptr, c1Tb, sc1, sh1,
        wthf, wphf, wgf, thb, phb, gb,
        nullptr, nullptr, thT, phT, g16);
    attn_k<<<1024, 256, 0, stream>>>(thT, phT, g16,
                                     O0f, O1f, O2f, O3f, part);
    conv1x1_k<<<512, 256, 0, stream>>>(O0f, O1f, O2f, O3f, part, w11f, Wbs, x,
                                       zT_hi);
    conv_mfma_k<1, 0, 0, 0><<<512, 256, 0, stream>>>(
        zT_hi, nullptr, nullptr, nullptr, nullptr,
        wc2f, nullptr, nullptr, nullptr, nullptr, nullptr,
        c2Tb, part, nullptr, nullptr, nullptr);
    statsB_k<<<64, 64, 0, stream>>>(part, bn2g, bn2b, sc2, sh2);
    bnreluT_k<<<256, 256, 0, stream>>>(c2Tb, sc2, sh2, out);
}